// Round 4
// baseline (477.159 us; speedup 1.0000x reference)
//
#include <hip/hip_runtime.h>
#include <hip/hip_bf16.h>
#include <stdint.h>

// Problem constants
#define INPUT_SIZE   736
#define PLANE_ELEMS  (736*736)        // 541696
#define N_RINGS      368
#define PATCH_LEN    768
#define EMBED        768
#define BATCH        32
#define KDIM         768              // 3*16*16
#define P_PER_BATCH  1104             // 23*48
#define OUT_BATCH_STRIDE 847872       // 768*1104

typedef __bf16 bf16x8 __attribute__((ext_vector_type(8)));
typedef float  floatx4 __attribute__((ext_vector_type(4)));

static __device__ __forceinline__ unsigned short bf16bits(float f) {
    __hip_bfloat16 h = __float2bfloat16(f);
    return *reinterpret_cast<unsigned short*>(&h);
}

// ---------------------------------------------------------------------------
// Kernel 1: cast conv_w (fp32, [E=768][K=768] flat) -> bf16 Wb
// ---------------------------------------------------------------------------
__global__ void wcast_kernel(const float* __restrict__ wsrc,
                             __hip_bfloat16* __restrict__ Wb) {
    int i = blockIdx.x * 256 + threadIdx.x;   // grid covers 589824 exactly
    Wb[i] = __float2bfloat16(wsrc[i]);
}

// ---------------------------------------------------------------------------
// Kernel 2 (R7): FUSED gather + GEMM.
//   Block = (n, band): 512 threads, LDS A-tile 48x768 bf16 (72KB, swizzled).
//   Phase 1 (gather): thread (rr=tid&15, jslot=tid>>4) lerps angle-pairs
//     j0 = jslot*2 + it*64 (it 0..11) for c 0..2 -> 72 scattered loads/thr.
//     Wave footprint = 16 rings x 8 angles (R5's compact polar patch).
//     Write (p=j0>>4, k=c*256+rr*16+(j0&15)) as ushort2 at XOR-swizzled
//     slot sw = (s8&~7)|((s8^p)&7), s8=k>>3  -> conflict-free b128 reads.
//   Phase 2 (gemm): 8 waves, 2 e-passes of 384; per wave/pass 48m x 48e =
//     acc[3][3]. A-frags from LDS (swizzled), B-frags DIRECT from global Wb
//     (1.2MB, L2-resident; per-e-row the 4 quads read one 64B line).
//     No barriers after the single syncthreads -> waves free-run; one
//     block's MFMA overlaps the co-resident block's gather latency.
//   Epilogue: float4 stores; per wave-store 16 e-rows x 64B full lines.
//   Eliminates: A HBM round-trip (53MB write + ~330MB read), 2 launches,
//   gather<->gemm serialization.
// ---------------------------------------------------------------------------
__global__ __launch_bounds__(512, 4) void fused_kernel(
        const float* __restrict__ x,          // (32,3,736,736)
        const int*   __restrict__ idx0,       // (368*768,)
        const int*   __restrict__ idx1,
        const float* __restrict__ w,
        const __hip_bfloat16* __restrict__ Wb,// [768][768] (E,K)
        const float* __restrict__ cb,         // [768]
        float* __restrict__ out)              // [32][768][1104]
{
    __shared__ __hip_bfloat16 Alds[48 * 768];   // 72 KiB

    const int n    = blockIdx.x;   // 0..31
    const int band = blockIdx.y;   // 0..22
    const int tid  = threadIdx.x;

    // ---------------- phase 1: gather + lerp -> LDS ----------------
    {
        const int rr    = tid & 15;          // ring within band
        const int jslot = tid >> 4;          // 0..31 (angle-pair slot)
        const int r     = band * 16 + rr;
        const float* pl0 = x + (size_t)(n * 3 + 0) * PLANE_ELEMS;
        const float* pl1 = x + (size_t)(n * 3 + 1) * PLANE_ELEMS;
        const float* pl2 = x + (size_t)(n * 3 + 2) * PLANE_ELEMS;

        #pragma unroll 2
        for (int it = 0; it < 12; it++) {
            const int j0 = jslot * 2 + it * 64;      // even angle of the pair
            const int t  = r * PATCH_LEN + j0;
            int2   i0p = *(const int2*)(idx0 + t);   // 8B-aligned (j0 even)
            int2   i1p = *(const int2*)(idx1 + t);
            float2 wp  = *(const float2*)(w + t);
            const int pl  = j0 >> 4;                 // patch col 0..47
            const int klo = j0 & 15;                 // even

            #pragma unroll
            for (int c = 0; c < 3; c++) {
                const float* pp = (c == 0) ? pl0 : (c == 1) ? pl1 : pl2;
                float va = pp[i0p.x] * (1.0f - wp.x) + pp[i1p.x] * wp.x;
                float vb = pp[i0p.y] * (1.0f - wp.y) + pp[i1p.y] * wp.y;
                const int k  = c * 256 + rr * 16 + klo;
                const int s8 = k >> 3;
                const int sw = (s8 & ~7) | ((s8 ^ pl) & 7);   // XOR swizzle
                *(ushort2*)((unsigned short*)Alds + pl * 768 + sw * 8 + (k & 7))
                    = make_ushort2(bf16bits(va), bf16bits(vb));
            }
        }
    }
    __syncthreads();

    // ---------------- phase 2: GEMM (no further barriers) ----------------
    const int lane = tid & 63;
    const int wv   = tid >> 6;     // 0..7
    const int quad = lane >> 4;
    const int l16  = lane & 15;

    float* outBase = out + (size_t)n * OUT_BATCH_STRIDE + band * 48;

    #pragma unroll
    for (int pass = 0; pass < 2; pass++) {
        const int e0w = pass * 384 + wv * 48;

        floatx4 acc[3][3];
        #pragma unroll
        for (int i = 0; i < 3; i++)
            #pragma unroll
            for (int j = 0; j < 3; j++)
                acc[i][j] = (floatx4){0.f, 0.f, 0.f, 0.f};

        #pragma unroll 2
        for (int kt = 0; kt < 24; kt++) {
            bf16x8 af[3], bfr[3];
            const int s8 = kt * 4 + quad;
            #pragma unroll
            for (int mt = 0; mt < 3; mt++) {
                const int row = mt * 16 + l16;
                const int sw  = (s8 & ~7) | ((s8 ^ row) & 7);
                af[mt] = *(const bf16x8*)(Alds + row * 768 + sw * 8);
            }
            #pragma unroll
            for (int ni = 0; ni < 3; ni++) {
                const int e = e0w + ni * 16 + l16;
                bfr[ni] = *(const bf16x8*)(Wb + (size_t)e * KDIM + kt * 32 + quad * 8);
            }
            #pragma unroll
            for (int mt = 0; mt < 3; mt++)
                #pragma unroll
                for (int ni = 0; ni < 3; ni++)
                    acc[mt][ni] = __builtin_amdgcn_mfma_f32_16x16x32_bf16(
                                      af[mt], bfr[ni], acc[mt][ni], 0, 0, 0);
        }

        // epilogue for this pass: full-line float4 stores
        #pragma unroll
        for (int ni = 0; ni < 3; ni++) {
            const int eg = e0w + ni * 16 + l16;
            const float bias = cb[eg];
            #pragma unroll
            for (int mt = 0; mt < 3; mt++) {
                const int pl = mt * 16 + quad * 4;
                floatx4 v = acc[mt][ni];
                v[0] += bias; v[1] += bias; v[2] += bias; v[3] += bias;
                *(floatx4*)(outBase + (size_t)eg * P_PER_BATCH + pl) = v;
            }
        }
    }
}

// ---------------------------------------------------------------------------
extern "C" void kernel_launch(void* const* d_in, const int* in_sizes, int n_in,
                              void* d_out, int out_size, void* d_ws, size_t ws_size,
                              hipStream_t stream) {
    const float* x      = (const float*)d_in[0];   // (32,3,736,736)
    const float* conv_w = (const float*)d_in[1];   // (768,3,16,16) = (768,768)
    const float* conv_b = (const float*)d_in[2];   // (768,)
    const int*   idx0   = (const int*)  d_in[3];   // (368*768,)
    const int*   idx1   = (const int*)  d_in[4];
    const float* w      = (const float*)d_in[5];
    float* out = (float*)d_out;

    __hip_bfloat16* Wb = (__hip_bfloat16*)d_ws;    // 1.2 MB

    // 1) weight cast: 589824 elements
    wcast_kernel<<<dim3(EMBED * KDIM / 256), dim3(256), 0, stream>>>(conv_w, Wb);

    // 2) fused gather + GEMM + bias -> out : one block per (n, band)
    fused_kernel<<<dim3(BATCH, 23), dim3(512), 0, stream>>>(
        x, idx0, idx1, w, Wb, conv_b, out);
}